// Round 5
// baseline (330.198 us; speedup 1.0000x reference)
//
#include <hip/hip_runtime.h>

#define B_BATCH 512
#define NPB     500
#define DIM     128
#define VOCAB   50000
#define MAXD    40
#define SLICE   32
#define NSLICE  (DIM / SLICE)   // 4

// ---------------- E = emb @ Wc + bc ----------------
// 64x64 output tile per block, 256 threads, 4x4 micro-tile per thread.
// A-operand staged TRANSPOSED (sEt[k][r], stride 68 = b128-aligned + spreads
// banks) so the k-loop is 2x ds_read_b128 (~18 LDS cyc) vs 32 VALU cyc/wave:
// VALU-bound, unlike the previous version (36 LDS vs 32 VALU -> LDS-bound).
__global__ __launch_bounds__(256) void gemm_E(const float* __restrict__ emb,
                                              const float* __restrict__ Wc,
                                              const float* __restrict__ bc,
                                              float* __restrict__ E) {
    __shared__ float sW[DIM * 64];      // [k][c] 32 KB
    __shared__ float sEt[DIM * 68];     // [k][r] transposed, 34.8 KB
    const int tid     = threadIdx.x;
    const int rowBase = (blockIdx.x >> 1) * 64;
    const int colBase = (blockIdx.x & 1) * 64;

    // stage Wc tile: 128k x 64c = 2048 float4
    for (int i = tid; i < DIM * 64 / 4; i += 256) {
        int k  = i >> 4;
        int c4 = (i & 15) * 4;
        *(float4*)&sW[k * 64 + c4] = *(const float4*)&Wc[k * DIM + colBase + c4];
    }
    // stage emb tile transposed: 64r x 128k scalars (coalesced reads)
    for (int i = tid; i < 64 * DIM; i += 256) {
        int r = i >> 7;
        int k = i & 127;
        float v = (rowBase + r < VOCAB) ? emb[(long long)(rowBase + r) * DIM + k] : 0.f;
        sEt[k * 68 + r] = v;
    }
    __syncthreads();

    const int r0 = (tid >> 4) * 4;      // 0..60
    const int c4 = (tid & 15) * 4;      // 0..60
    float4 a0 = make_float4(0.f,0.f,0.f,0.f), a1 = a0, a2 = a0, a3 = a0;
    #pragma unroll 4
    for (int k = 0; k < DIM; ++k) {
        float4 e = *(float4*)&sEt[k * 68 + r0];
        float4 w = *(float4*)&sW [k * 64 + c4];
        a0.x += e.x*w.x; a0.y += e.x*w.y; a0.z += e.x*w.z; a0.w += e.x*w.w;
        a1.x += e.y*w.x; a1.y += e.y*w.y; a1.z += e.y*w.z; a1.w += e.y*w.w;
        a2.x += e.z*w.x; a2.y += e.z*w.y; a2.z += e.z*w.z; a2.w += e.z*w.w;
        a3.x += e.w*w.x; a3.y += e.w*w.y; a3.z += e.w*w.z; a3.w += e.w*w.w;
    }
    float4 b4 = *(const float4*)&bc[colBase + c4];
    a0.x += b4.x; a0.y += b4.y; a0.z += b4.z; a0.w += b4.w;
    a1.x += b4.x; a1.y += b4.y; a1.z += b4.z; a1.w += b4.w;
    a2.x += b4.x; a2.y += b4.y; a2.z += b4.z; a2.w += b4.w;
    a3.x += b4.x; a3.y += b4.y; a3.z += b4.z; a3.w += b4.w;

    #pragma unroll
    for (int u = 0; u < 4; ++u) {
        int r = rowBase + r0 + u;
        if (r < VOCAB) {
            float4 a = (u == 0) ? a0 : (u == 1) ? a1 : (u == 2) ? a2 : a3;
            *(float4*)&E[(long long)r * DIM + colBase + c4] = a;
        }
    }
}

// ---------------- fused per-(tree, 32-dim-slice) kernel ----------------
// grid = 512 trees x 4 slices, 512 threads. Node slice = 128 contiguous,
// 128B-aligned bytes = exactly 2 full cache lines (100% line use). Gather is
// unrolled 8-deep (8 independent dwordx4 in flight). Propagation: 40-level
// bottom-up entirely in LDS (ds_add_f32 + __syncthreads), fused running max.
__global__ __launch_bounds__(512) void tree_slice(const int* __restrict__ tokens,
                                                  const int* __restrict__ parent,
                                                  const int* __restrict__ depth,
                                                  const float* __restrict__ E,
                                                  float* __restrict__ out) {
    const int b   = blockIdx.x >> 2;    // tree
    const int s   = blockIdx.x & 3;     // dim-slice
    const int tid = threadIdx.x;
    const long long nbase = (long long)b * NPB;

    __shared__ float vL[NPB * SLICE];          // 64000 B
    __shared__ unsigned short bucket[NPB];     // 1000 B
    __shared__ unsigned short par[NPB];        // 1000 B
    __shared__ unsigned short dep[NPB];        // 1000 B
    __shared__ int tokL[NPB];                  // 2000 B
    __shared__ int hist[MAXD + 1];
    __shared__ int off [MAXD + 1];
    __shared__ int cur [MAXD + 1];
    __shared__ float smax[16][SLICE];          // 2048 B
    __shared__ int sdmax;

    if (tid <= MAXD) hist[tid] = 0;
    if (tid == 0) sdmax = 0;
    __syncthreads();

    // pass 1: stage meta (single round: 512 threads >= 500 nodes)
    if (tid < NPB) {
        int n = tid;
        int d = depth[nbase + n];
        dep[n]  = (unsigned short)d;
        par[n]  = (unsigned short)(n == 0 ? 0 : (int)(parent[nbase + n] - nbase));
        tokL[n] = tokens[nbase + n];
        if (n > 0) { atomicAdd(&hist[d], 1); atomicMax(&sdmax, d); }
    }
    __syncthreads();

    // exclusive prefix over hist[1..40] via wave-0 shuffle scan
    if (tid < 64) {
        int h = (tid >= 1 && tid <= MAXD) ? hist[tid] : 0;
        int x = h;
        #pragma unroll
        for (int o = 1; o < 64; o <<= 1) {
            int y = __shfl_up(x, o, 64);
            if (tid >= o) x += y;
        }
        if (tid >= 1 && tid <= MAXD) { off[tid] = x - h; cur[tid] = x - h; }
    }
    __syncthreads();

    // pass 2: bucket nodes by depth (LDS atomics)
    if (tid >= 1 && tid < NPB)
        bucket[atomicAdd(&cur[dep[tid]], 1)] = (unsigned short)tid;

    // gather this 32-dim slice of E[tok[n]]: 4000 float4 tasks, unrolled 8-deep
    {
        const int base = s * SLICE;
        float4 tmp[7];
        #pragma unroll
        for (int u = 0; u < 7; ++u) {
            int t = tid + u * 512;              // < 4000 always (max 3583)
            int n = t >> 3, q = (t & 7) * 4;
            tmp[u] = *(const float4*)&E[(long long)tokL[n] * DIM + base + q];
        }
        float4 last;
        int tl = tid + 7 * 512;
        bool has = (tl < NPB * 8);
        if (has) {
            int n = tl >> 3, q = (tl & 7) * 4;
            last = *(const float4*)&E[(long long)tokL[n] * DIM + base + q];
        }
        #pragma unroll
        for (int u = 0; u < 7; ++u) {
            int t = tid + u * 512;
            int n = t >> 3, q = (t & 7) * 4;
            *(float4*)&vL[n * SLICE + q] = tmp[u];
        }
        if (has) {
            int n = tl >> 3, q = (tl & 7) * 4;
            *(float4*)&vL[n * SLICE + q] = last;
        }
    }
    __syncthreads();

    // level loop, deepest first; ds_add_f32, bank-clean (j = bank, 2 lanes/bank)
    const int dmax = sdmax;
    const int j = tid & 31;
    float m = -INFINITY;
    for (int d = dmax; d >= 1; --d) {
        int c = hist[d];
        int o = off[d];
        for (int i = tid; i < c * SLICE; i += 512) {
            int n = bucket[o + (i >> 5)];
            float x = vL[n * SLICE + j];     // final: children were prior levels
            atomicAdd(&vL[par[n] * SLICE + j], x);
            m = fmaxf(m, x);
        }
        __syncthreads();
    }

    // reduce 16 warp-group maxes + root row, ReLU, store
    smax[tid >> 5][j] = m;
    __syncthreads();
    if (tid >= 32 && tid < 64) {
        // let lanes 32..63 also help? no — keep single clean reducer below
    }
    if (tid < SLICE) {
        float mm = smax[0][tid];
        #pragma unroll
        for (int g = 1; g < 16; ++g) mm = fmaxf(mm, smax[g][tid]);
        mm = fmaxf(mm, vL[tid]);             // root (node 0) final value
        out[b * DIM + s * SLICE + tid] = fmaxf(mm, 0.0f);
    }
}

extern "C" void kernel_launch(void* const* d_in, const int* in_sizes, int n_in,
                              void* d_out, int out_size, void* d_ws, size_t ws_size,
                              hipStream_t stream) {
    const int*   tokens = (const int*)d_in[0];
    const int*   parent = (const int*)d_in[1];
    const int*   depth  = (const int*)d_in[2];
    // d_in[3] = node2batch (unused: node2batch[n] == n / 500 by construction)
    const float* emb    = (const float*)d_in[4];
    const float* Wc     = (const float*)d_in[5];
    const float* bc     = (const float*)d_in[6];
    float*       out    = (float*)d_out;

    float* E = (float*)d_ws;   // VOCAB*DIM floats (25.6 MB)

    gemm_E<<<((VOCAB + 63) / 64) * 2, 256, 0, stream>>>(emb, Wc, bc, E);
    tree_slice<<<B_BATCH * NSLICE, 512, 0, stream>>>(tokens, parent, depth, E, out);
}

// Round 6
// 235.801 us; speedup vs baseline: 1.4003x; 1.4003x over previous
//
#include <hip/hip_runtime.h>

#define B_BATCH 512
#define NPB     500
#define DIM     128
#define VOCAB   50000

// ---------------- per-tree prep: DFS order via linked-list insertion ----------------
// Insert node n immediately after its parent (n increasing) => valid preorder
// (children in decreasing order). snode[n] = next[par] captured at insertion is
// the first node AFTER n's subtree, forever => end(n) = tin(snode)-1.
// One block per tree; the two serial walks are ~500 LDS steps each (thread 0),
// all 512 trees run in parallel.
__global__ __launch_bounds__(128) void prep_k(const int* __restrict__ tokens,
                                              const int* __restrict__ parent,
                                              int* __restrict__ tokD,
                                              unsigned short* __restrict__ endD) {
    const int b = blockIdx.x, tid = threadIdx.x;
    const long long base = (long long)b * NPB;
    __shared__ int parL[NPB];
    __shared__ int tokL[NPB];
    __shared__ int nxt [NPB];
    __shared__ int snode[NPB];
    __shared__ unsigned short tin[NPB];
    __shared__ int tmpTok[NPB];
    __shared__ unsigned short tmpEnd[NPB];

    for (int n = tid; n < NPB; n += 128) {
        parL[n] = (n == 0) ? -1 : (int)(parent[base + n] - base);
        tokL[n] = tokens[base + n];
        nxt[n]  = -1;
    }
    __syncthreads();

    if (tid == 0) {
        for (int n = 1; n < NPB; ++n) {      // build list
            int p = parL[n];
            int s = nxt[p];
            nxt[n] = s; snode[n] = s; nxt[p] = n;
        }
        int cur = 0, t = 0;                  // walk list -> DFS positions
        while (cur >= 0) { tin[cur] = (unsigned short)t++; cur = nxt[cur]; }
    }
    __syncthreads();

    for (int n = tid; n < NPB; n += 128) {   // end positions + scatter to DFS order
        int e;
        if (n == 0) e = NPB - 1;
        else { int s = snode[n]; e = (s < 0) ? (NPB - 1) : ((int)tin[s] - 1); }
        int dt = tin[n];
        tmpTok[dt] = tokL[n];
        tmpEnd[dt] = (unsigned short)e;
    }
    __syncthreads();
    for (int t = tid; t < NPB; t += 128) {   // coalesced global emit
        tokD[base + t] = tmpTok[t];
        endD[base + t] = tmpEnd[t];
    }
}

// ---------------- E = emb @ Wc + bc ----------------
// 128x128 output tile per block, 256 threads, 8x8 micro-tile.
// A staged [r][k] stride 129 => the 8 per-k A-reads hit 4 DISTINCT banks
// across the wave's 4 row-groups (129%32==1) -> conflict-free broadcasts.
// W b128 reads. ~64 FMA per (8 scalar + 2 b128) LDS reads.
__global__ __launch_bounds__(256) void gemm_E(const float* __restrict__ emb,
                                              const float* __restrict__ Wc,
                                              const float* __restrict__ bc,
                                              float* __restrict__ E) {
    __shared__ float sA[128 * 129];   // 66 KB
    __shared__ float sW[128 * 128];   // 64 KB
    const int tid = threadIdx.x;
    const int rowBase = blockIdx.x * 128;

    for (int i = tid; i < 4096; i += 256)          // Wc is [k][c] row-major: flat copy
        ((float4*)sW)[i] = ((const float4*)Wc)[i];

    for (int i = tid; i < 128 * 32; i += 256) {    // emb rows -> sA stride 129
        int r = i >> 5, k4 = (i & 31) * 4;
        float4 v = make_float4(0.f, 0.f, 0.f, 0.f);
        if (rowBase + r < VOCAB)
            v = *(const float4*)&emb[(long long)(rowBase + r) * DIM + k4];
        sA[r * 129 + k4 + 0] = v.x;
        sA[r * 129 + k4 + 1] = v.y;
        sA[r * 129 + k4 + 2] = v.z;
        sA[r * 129 + k4 + 3] = v.w;
    }
    __syncthreads();

    const int r0 = (tid >> 4) * 8;    // 0..120
    const int c0 = (tid & 15) * 8;    // 0..120
    float acc[8][8];
    #pragma unroll
    for (int u = 0; u < 8; ++u)
        #pragma unroll
        for (int q = 0; q < 8; ++q) acc[u][q] = 0.f;

    #pragma unroll 4
    for (int k = 0; k < DIM; ++k) {
        float4 w0 = *(float4*)&sW[k * 128 + c0];
        float4 w1 = *(float4*)&sW[k * 128 + c0 + 4];
        float a[8];
        #pragma unroll
        for (int u = 0; u < 8; ++u) a[u] = sA[(r0 + u) * 129 + k];
        #pragma unroll
        for (int u = 0; u < 8; ++u) {
            acc[u][0] += a[u] * w0.x; acc[u][1] += a[u] * w0.y;
            acc[u][2] += a[u] * w0.z; acc[u][3] += a[u] * w0.w;
            acc[u][4] += a[u] * w1.x; acc[u][5] += a[u] * w1.y;
            acc[u][6] += a[u] * w1.z; acc[u][7] += a[u] * w1.w;
        }
    }

    float4 b0 = *(const float4*)&bc[c0];
    float4 b1 = *(const float4*)&bc[c0 + 4];
    #pragma unroll
    for (int u = 0; u < 8; ++u) {
        int r = rowBase + r0 + u;
        if (r < VOCAB) {
            float4 o0 = make_float4(acc[u][0] + b0.x, acc[u][1] + b0.y,
                                    acc[u][2] + b0.z, acc[u][3] + b0.w);
            float4 o1 = make_float4(acc[u][4] + b1.x, acc[u][5] + b1.y,
                                    acc[u][6] + b1.z, acc[u][7] + b1.w);
            *(float4*)&E[(long long)r * DIM + c0]     = o0;
            *(float4*)&E[(long long)r * DIM + c0 + 4] = o1;
        }
    }
}

// ---------------- fused gather + prefix-scan + subtree-max ----------------
// grid = 512 trees x 4 dim-slices, 512 threads. Phases (3 barriers total, no
// atomics): gather E slices in DFS order -> blocked inclusive scan along DFS
// (16 chunks x 32 dims; chunk values live in 32 VGPRs) -> subtree sums as
// S[end]-S[tin-1], running max, relu, store.
__global__ __launch_bounds__(512) void scan_k(const int* __restrict__ tokD,
                                              const unsigned short* __restrict__ endD,
                                              const float* __restrict__ E,
                                              float* __restrict__ out) {
    const int b = blockIdx.x >> 2, s = blockIdx.x & 3, tid = threadIdx.x;
    const long long base = (long long)b * NPB;
    __shared__ float S[NPB * 32];             // 64000 B
    __shared__ unsigned short endL[NPB];      // 1000 B
    __shared__ float partials[16 * 32];       // 2048 B
    __shared__ float wmax[8 * 32];            // 1024 B

    if (tid < NPB) endL[tid] = endD[base + tid];

    // gather: 4000 float4 tasks, batched 8-deep for MLP
    {
        int    tk[8];
        float4 val[8];
        #pragma unroll
        for (int u = 0; u < 8; ++u) {
            int i = tid + u * 512;
            tk[u] = (i < NPB * 8) ? tokD[base + (i >> 3)] : 0;
        }
        #pragma unroll
        for (int u = 0; u < 8; ++u) {
            int i = tid + u * 512;
            if (i < NPB * 8)
                val[u] = *(const float4*)&E[(long long)tk[u] * DIM + s * 32 + (i & 7) * 4];
        }
        #pragma unroll
        for (int u = 0; u < 8; ++u) {
            int i = tid + u * 512;
            if (i < NPB * 8)
                *(float4*)&S[(i >> 3) * 32 + (i & 7) * 4] = val[u];
        }
    }
    __syncthreads();

    // blocked inclusive scan along t, per dim j (bank j constant, 2 lanes/bank = free)
    const int j = tid & 31, c = tid >> 5;     // chunk c: t = 32c .. 32c+31
    float x[32];
    float run = 0.f;
    #pragma unroll
    for (int i2 = 0; i2 < 32; ++i2) {
        int t = c * 32 + i2;
        float v = (t < NPB) ? S[t * 32 + j] : 0.f;
        run += v; x[i2] = run;
    }
    partials[c * 32 + j] = run;
    __syncthreads();
    float off = 0.f;
    for (int cc = 0; cc < c; ++cc) off += partials[cc * 32 + j];
    #pragma unroll
    for (int i2 = 0; i2 < 32; ++i2) {
        int t = c * 32 + i2;
        if (t < NPB) S[t * 32 + j] = x[i2] + off;
    }
    __syncthreads();

    // extract: subtree_sum(t) = S[end[t]] - S[t-1]; fused max
    float m = -INFINITY;
    #pragma unroll 4
    for (int u = 0; u < 32; ++u) {
        int i = tid + u * 512;                // i&31 == j
        if (i < NPB * 32) {
            int t = i >> 5;
            int e = endL[t];
            float hi = S[e * 32 + j];
            float lo = (t > 0) ? S[(t - 1) * 32 + j] : 0.f;
            m = fmaxf(m, hi - lo);
        }
    }
    m = fmaxf(m, __shfl_down(m, 32));         // fold upper half-wave
    if ((tid & 63) < 32) wmax[(tid >> 6) * 32 + j] = m;
    __syncthreads();
    if (tid < 32) {
        float mm = wmax[tid];
        #pragma unroll
        for (int w = 1; w < 8; ++w) mm = fmaxf(mm, wmax[w * 32 + tid]);
        out[b * DIM + s * 32 + tid] = fmaxf(mm, 0.0f);
    }
}

extern "C" void kernel_launch(void* const* d_in, const int* in_sizes, int n_in,
                              void* d_out, int out_size, void* d_ws, size_t ws_size,
                              hipStream_t stream) {
    const int*   tokens = (const int*)d_in[0];
    const int*   parent = (const int*)d_in[1];
    // d_in[2] = depth (no longer needed), d_in[3] = node2batch (n/500)
    const float* emb    = (const float*)d_in[4];
    const float* Wc     = (const float*)d_in[5];
    const float* bc     = (const float*)d_in[6];
    float*       out    = (float*)d_out;

    float*          E    = (float*)d_ws;                       // 25.6 MB
    int*            tokD = (int*)(E + (long long)VOCAB * DIM); // 1 MB
    unsigned short* endD = (unsigned short*)(tokD + B_BATCH * NPB); // 0.5 MB

    prep_k<<<B_BATCH, 128, 0, stream>>>(tokens, parent, tokD, endD);
    gemm_E<<<(VOCAB + 127) / 128, 256, 0, stream>>>(emb, Wc, bc, E);
    scan_k<<<B_BATCH * 4, 512, 0, stream>>>(tokD, endD, E, out);
}

// Round 7
// 201.531 us; speedup vs baseline: 1.6385x; 1.1700x over previous
//
#include <hip/hip_runtime.h>

#define B_BATCH 512
#define NPB     500
#define DIM     128
#define VOCAB   50000
#define MAXD    40

// ---------------- per-tree prep: DFS order, fully parallel ----------------
// Preorder with children visited in INCREASING index order:
//   tin(n) = tin(par) + 1 + sum of sizes of smaller-index siblings
//   end(n) = tin(n) + size(n) - 1.
// size[]: level-synchronous bottom-up (depth input!). Sibling prefix: uniform
// 500-iter broadcast loop over packed par|size. tin: top-down by level.
// No serial linked-list walks (round-6 prep was ~1000 dependent LDS reads).
__global__ __launch_bounds__(256) void prep_k(const int* __restrict__ tokens,
                                              const int* __restrict__ parent,
                                              const int* __restrict__ depth,
                                              int* __restrict__ tokD,
                                              unsigned short* __restrict__ endD) {
    const int b = blockIdx.x, tid = threadIdx.x;
    const long long base = (long long)b * NPB;
    __shared__ unsigned short parL[NPB];
    __shared__ unsigned short depL[NPB];
    __shared__ int   tokL[NPB];
    __shared__ int   sizeL[NPB];
    __shared__ int   pack[NPB];
    __shared__ unsigned short sibp[NPB];
    __shared__ unsigned short tinL[NPB];
    __shared__ unsigned short bucket[NPB];
    __shared__ int hist[MAXD + 1], off[MAXD + 1], cur[MAXD + 1];
    __shared__ int tmpTok[NPB];
    __shared__ unsigned short tmpEnd[NPB];
    __shared__ int sdmax;

    if (tid <= MAXD) hist[tid] = 0;
    __syncthreads();
    for (int n = tid; n < NPB; n += 256) {
        int d = depth[base + n];
        depL[n]  = (unsigned short)d;
        parL[n]  = (unsigned short)(n == 0 ? 0 : (int)(parent[base + n] - base));
        tokL[n]  = tokens[base + n];
        sizeL[n] = 1;
        if (n > 0) atomicAdd(&hist[d], 1);
    }
    __syncthreads();

    // wave 0: exclusive prefix over hist[1..40] + max nonzero depth
    if (tid < 64) {
        int h = (tid >= 1 && tid <= MAXD) ? hist[tid] : 0;
        int x = h;
        #pragma unroll
        for (int o = 1; o < 64; o <<= 1) { int y = __shfl_up(x, o, 64); if (tid >= o) x += y; }
        if (tid >= 1 && tid <= MAXD) { off[tid] = x - h; cur[tid] = x - h; }
        int dm = (h > 0) ? tid : 0;
        #pragma unroll
        for (int o = 32; o; o >>= 1) dm = max(dm, __shfl_down(dm, o));
        if (tid == 0) sdmax = dm;
    }
    __syncthreads();

    for (int n = 1 + tid; n < NPB; n += 256)
        bucket[atomicAdd(&cur[depL[n]], 1)] = (unsigned short)n;
    __syncthreads();
    const int dmax = sdmax;

    // bottom-up subtree sizes, level-synchronous (children final before parent)
    for (int d = dmax; d >= 1; --d) {
        int c = hist[d], o = off[d];
        for (int i = tid; i < c; i += 256) {
            int n = bucket[o + i];
            atomicAdd(&sizeL[parL[n]], sizeL[n]);
        }
        __syncthreads();
    }

    for (int n = tid; n < NPB; n += 256) pack[n] = (int)parL[n] | (sizeL[n] << 16);
    __syncthreads();

    // sibp[n] = sum of sizes of same-parent nodes with smaller index
    // uniform loop; pack[m] is a 1-address broadcast read per iteration (free)
    {
        int n0 = tid, n1 = tid + 256;
        int p0 = parL[n0];
        int p1 = (n1 < NPB) ? parL[n1] : -1;
        int a0 = 0, a1 = 0;
        for (int m = 1; m < NPB; ++m) {
            int pk = pack[m];
            int pm = pk & 0xffff, sm = pk >> 16;
            if (m < n0 && pm == p0) a0 += sm;
            if (m < n1 && pm == p1) a1 += sm;
        }
        if (n0 >= 1) sibp[n0] = (unsigned short)a0;
        if (n1 >= 1 && n1 < NPB) sibp[n1] = (unsigned short)a1;
        if (tid == 0) tinL[0] = 0;
    }
    __syncthreads();

    // top-down preorder positions, level-synchronous
    for (int d = 1; d <= dmax; ++d) {
        int c = hist[d], o = off[d];
        for (int i = tid; i < c; i += 256) {
            int n = bucket[o + i];
            tinL[n] = (unsigned short)((int)tinL[parL[n]] + 1 + (int)sibp[n]);
        }
        __syncthreads();
    }

    // scatter to DFS order, then coalesced emit
    for (int n = tid; n < NPB; n += 256) {
        int t = tinL[n];
        tmpTok[t] = tokL[n];
        tmpEnd[t] = (unsigned short)(t + sizeL[n] - 1);
    }
    __syncthreads();
    for (int t = tid; t < NPB; t += 256) {
        tokD[base + t] = tmpTok[t];
        endD[base + t] = tmpEnd[t];
    }
}

// ---------------- E = emb @ Wc + bc ----------------
// 128x128 tile, 256 threads, 8x8 micro, k split into two 64-k stages so LDS
// = 33.8 + 32 = 66 KB -> 2 blocks/CU (2 waves/SIMD: latency hiding; round-6
// version was 130 KB -> 1 wave/SIMD, VALUBusy 20%).
// A staged transposed [k][r] stride 132: A-reads are 2 b128, 8 addrs/wave
// covering all 32 banks exactly once (conflict-free). W-reads split c1 /
// c1+64: 2 addrs per bank group = free (round-6 c0*8 pattern was 4-way).
__global__ __launch_bounds__(256, 2) void gemm_E(const float* __restrict__ emb,
                                                 const float* __restrict__ Wc,
                                                 const float* __restrict__ bc,
                                                 float* __restrict__ E) {
    __shared__ float sAt[64 * 132];   // [k][r], 33.8 KB
    __shared__ float sW [64 * 128];   // [k][c], 32 KB
    const int tid = threadIdx.x;
    const int rowBase = blockIdx.x * 128;
    const int r0 = (tid >> 4) * 8;
    const int c1 = (tid & 15) * 4;

    float acc[8][8];
    #pragma unroll
    for (int u = 0; u < 8; ++u)
        #pragma unroll
        for (int q = 0; q < 8; ++q) acc[u][q] = 0.f;

    for (int kh = 0; kh < 2; ++kh) {
        if (kh) __syncthreads();
        for (int i = tid; i < 2048; i += 256)
            ((float4*)sW)[i] = ((const float4*)Wc)[kh * 2048 + i];
        for (int i = tid; i < 2048; i += 256) {
            int r  = i >> 4;
            int kq = (i & 15) * 4;
            float4 v = make_float4(0.f, 0.f, 0.f, 0.f);
            if (rowBase + r < VOCAB)
                v = *(const float4*)&emb[(long long)(rowBase + r) * DIM + kh * 64 + kq];
            sAt[(kq + 0) * 132 + r] = v.x;
            sAt[(kq + 1) * 132 + r] = v.y;
            sAt[(kq + 2) * 132 + r] = v.z;
            sAt[(kq + 3) * 132 + r] = v.w;
        }
        __syncthreads();

        #pragma unroll 4
        for (int k = 0; k < 64; ++k) {
            float4 a0 = *(float4*)&sAt[k * 132 + r0];
            float4 a1 = *(float4*)&sAt[k * 132 + r0 + 4];
            float4 w0 = *(float4*)&sW [k * 128 + c1];
            float4 w1 = *(float4*)&sW [k * 128 + 64 + c1];
            float av[8] = {a0.x, a0.y, a0.z, a0.w, a1.x, a1.y, a1.z, a1.w};
            #pragma unroll
            for (int u = 0; u < 8; ++u) {
                acc[u][0] += av[u] * w0.x; acc[u][1] += av[u] * w0.y;
                acc[u][2] += av[u] * w0.z; acc[u][3] += av[u] * w0.w;
                acc[u][4] += av[u] * w1.x; acc[u][5] += av[u] * w1.y;
                acc[u][6] += av[u] * w1.z; acc[u][7] += av[u] * w1.w;
            }
        }
    }

    float4 b0 = *(const float4*)&bc[c1];
    float4 b1 = *(const float4*)&bc[64 + c1];
    #pragma unroll
    for (int u = 0; u < 8; ++u) {
        int r = rowBase + r0 + u;
        if (r < VOCAB) {
            float4 o0 = make_float4(acc[u][0]+b0.x, acc[u][1]+b0.y, acc[u][2]+b0.z, acc[u][3]+b0.w);
            float4 o1 = make_float4(acc[u][4]+b1.x, acc[u][5]+b1.y, acc[u][6]+b1.z, acc[u][7]+b1.w);
            *(float4*)&E[(long long)r * DIM + c1]      = o0;
            *(float4*)&E[(long long)r * DIM + 64 + c1] = o1;
        }
    }
}

// ---------------- fused gather + prefix-scan + subtree-max ----------------
// In-place scan (running sum written back to S) + chunk offsets folded into
// the extract phase: NOTHING lives across a barrier in a register array, so
// the round-6 scratch spill (128 MB of WRITE traffic) is gone.
__global__ __launch_bounds__(512) void scan_k(const int* __restrict__ tokD,
                                              const unsigned short* __restrict__ endD,
                                              const float* __restrict__ E,
                                              float* __restrict__ out) {
    const int b = blockIdx.x >> 2, s = blockIdx.x & 3, tid = threadIdx.x;
    const long long base = (long long)b * NPB;
    __shared__ float S[NPB * 32];             // 64000 B
    __shared__ unsigned short endL[NPB];
    __shared__ float partials[16 * 32];
    __shared__ float chunkoff[16 * 32];
    __shared__ float wmax[8 * 32];

    if (tid < NPB) endL[tid] = endD[base + tid];

    {   // gather, batched 8-deep for MLP
        int tk[8];
        #pragma unroll
        for (int u = 0; u < 8; ++u) {
            int i = tid + u * 512;
            tk[u] = (i < NPB * 8) ? tokD[base + (i >> 3)] : 0;
        }
        float4 val[8];
        #pragma unroll
        for (int u = 0; u < 8; ++u) {
            int i = tid + u * 512;
            if (i < NPB * 8)
                val[u] = *(const float4*)&E[(long long)tk[u] * DIM + s * 32 + (i & 7) * 4];
        }
        #pragma unroll
        for (int u = 0; u < 8; ++u) {
            int i = tid + u * 512;
            if (i < NPB * 8)
                *(float4*)&S[(i >> 3) * 32 + (i & 7) * 4] = val[u];
        }
    }
    __syncthreads();

    const int j = tid & 31, c = tid >> 5;
    {   // in-place inclusive scan within chunk (bank j constant: 2-way = free)
        float run = 0.f;
        #pragma unroll 8
        for (int i2 = 0; i2 < 32; ++i2) {
            int t = c * 32 + i2;
            if (t < NPB) { run += S[t * 32 + j]; S[t * 32 + j] = run; }
        }
        partials[c * 32 + j] = run;
    }
    __syncthreads();
    {   // exclusive chunk offsets: one (c,j) pair per thread
        float o = 0.f;
        for (int cc = 0; cc < c; ++cc) o += partials[cc * 32 + j];
        chunkoff[c * 32 + j] = o;
    }
    __syncthreads();

    // subtree_sum(t) = (S[e]+off[e>>5]) - (S[t-1]+off[(t-1)>>5]); fused max
    float m = -INFINITY;
    #pragma unroll 4
    for (int u = 0; u < 32; ++u) {
        int i = tid + u * 512;                // i&31 == j
        if (i < NPB * 32) {
            int t = i >> 5;
            int e = endL[t];
            float hi = S[e * 32 + j] + chunkoff[(e >> 5) * 32 + j];
            float lo = (t > 0) ? S[(t - 1) * 32 + j] + chunkoff[((t - 1) >> 5) * 32 + j] : 0.f;
            m = fmaxf(m, hi - lo);
        }
    }
    m = fmaxf(m, __shfl_down(m, 32));
    if ((tid & 63) < 32) wmax[(tid >> 6) * 32 + j] = m;
    __syncthreads();
    if (tid < 32) {
        float mm = wmax[tid];
        #pragma unroll
        for (int w = 1; w < 8; ++w) mm = fmaxf(mm, wmax[w * 32 + tid]);
        out[b * DIM + s * 32 + tid] = fmaxf(mm, 0.0f);
    }
}

extern "C" void kernel_launch(void* const* d_in, const int* in_sizes, int n_in,
                              void* d_out, int out_size, void* d_ws, size_t ws_size,
                              hipStream_t stream) {
    const int*   tokens = (const int*)d_in[0];
    const int*   parent = (const int*)d_in[1];
    const int*   depth  = (const int*)d_in[2];
    // d_in[3] = node2batch (unused: node2batch[n] == n / 500 by construction)
    const float* emb    = (const float*)d_in[4];
    const float* Wc     = (const float*)d_in[5];
    const float* bc     = (const float*)d_in[6];
    float*       out    = (float*)d_out;

    float*          E    = (float*)d_ws;                            // 25.6 MB
    int*            tokD = (int*)(E + (long long)VOCAB * DIM);      // 1 MB
    unsigned short* endD = (unsigned short*)(tokD + B_BATCH * NPB); // 0.5 MB

    prep_k<<<B_BATCH, 256, 0, stream>>>(tokens, parent, depth, tokD, endD);
    gemm_E<<<(VOCAB + 127) / 128, 256, 0, stream>>>(emb, Wc, bc, E);
    scan_k<<<B_BATCH * 4, 512, 0, stream>>>(tokD, endD, E, out);
}

// Round 8
// 170.887 us; speedup vs baseline: 1.9323x; 1.1793x over previous
//
#include <hip/hip_runtime.h>

#define B_BATCH 512
#define NPB     500
#define DIM     128
#define VOCAB   50000
#define MAXD    40

// ---------------- per-tree prep: DFS order, fully parallel ----------------
__global__ __launch_bounds__(256) void prep_k(const int* __restrict__ tokens,
                                              const int* __restrict__ parent,
                                              const int* __restrict__ depth,
                                              int* __restrict__ tokD,
                                              unsigned short* __restrict__ endD) {
    const int b = blockIdx.x, tid = threadIdx.x;
    const long long base = (long long)b * NPB;
    __shared__ unsigned short parL[NPB];
    __shared__ unsigned short depL[NPB];
    __shared__ int   tokL[NPB];
    __shared__ int   sizeL[NPB];
    __shared__ int   pack[NPB];
    __shared__ unsigned short sibp[NPB];
    __shared__ unsigned short tinL[NPB];
    __shared__ unsigned short bucket[NPB];
    __shared__ int hist[MAXD + 1], off[MAXD + 1], cur[MAXD + 1];
    __shared__ int tmpTok[NPB];
    __shared__ unsigned short tmpEnd[NPB];
    __shared__ int sdmax;

    if (tid <= MAXD) hist[tid] = 0;
    __syncthreads();
    for (int n = tid; n < NPB; n += 256) {
        int d = depth[base + n];
        depL[n]  = (unsigned short)d;
        parL[n]  = (unsigned short)(n == 0 ? 0 : (int)(parent[base + n] - base));
        tokL[n]  = tokens[base + n];
        sizeL[n] = 1;
        if (n > 0) atomicAdd(&hist[d], 1);
    }
    __syncthreads();

    if (tid < 64) {
        int h = (tid >= 1 && tid <= MAXD) ? hist[tid] : 0;
        int x = h;
        #pragma unroll
        for (int o = 1; o < 64; o <<= 1) { int y = __shfl_up(x, o, 64); if (tid >= o) x += y; }
        if (tid >= 1 && tid <= MAXD) { off[tid] = x - h; cur[tid] = x - h; }
        int dm = (h > 0) ? tid : 0;
        #pragma unroll
        for (int o = 32; o; o >>= 1) dm = max(dm, __shfl_down(dm, o));
        if (tid == 0) sdmax = dm;
    }
    __syncthreads();

    for (int n = 1 + tid; n < NPB; n += 256)
        bucket[atomicAdd(&cur[depL[n]], 1)] = (unsigned short)n;
    __syncthreads();
    const int dmax = sdmax;

    for (int d = dmax; d >= 1; --d) {
        int c = hist[d], o = off[d];
        for (int i = tid; i < c; i += 256) {
            int n = bucket[o + i];
            atomicAdd(&sizeL[parL[n]], sizeL[n]);
        }
        __syncthreads();
    }

    for (int n = tid; n < NPB; n += 256) pack[n] = (int)parL[n] | (sizeL[n] << 16);
    __syncthreads();

    {
        int n0 = tid, n1 = tid + 256;
        int p0 = parL[n0];
        int p1 = (n1 < NPB) ? parL[n1] : -1;
        int a0 = 0, a1 = 0;
        for (int m = 1; m < NPB; ++m) {
            int pk = pack[m];
            int pm = pk & 0xffff, sm = pk >> 16;
            if (m < n0 && pm == p0) a0 += sm;
            if (m < n1 && pm == p1) a1 += sm;
        }
        if (n0 >= 1) sibp[n0] = (unsigned short)a0;
        if (n1 >= 1 && n1 < NPB) sibp[n1] = (unsigned short)a1;
        if (tid == 0) tinL[0] = 0;
    }
    __syncthreads();

    for (int d = 1; d <= dmax; ++d) {
        int c = hist[d], o = off[d];
        for (int i = tid; i < c; i += 256) {
            int n = bucket[o + i];
            tinL[n] = (unsigned short)((int)tinL[parL[n]] + 1 + (int)sibp[n]);
        }
        __syncthreads();
    }

    for (int n = tid; n < NPB; n += 256) {
        int t = tinL[n];
        tmpTok[t] = tokL[n];
        tmpEnd[t] = (unsigned short)(t + sizeL[n] - 1);
    }
    __syncthreads();
    for (int t = tid; t < NPB; t += 256) {
        tokD[base + t] = tmpTok[t];
        endD[base + t] = tmpEnd[t];
    }
}

// ---------------- E = emb @ Wc + bc (unchanged from r7) ----------------
__global__ __launch_bounds__(256, 2) void gemm_E(const float* __restrict__ emb,
                                                 const float* __restrict__ Wc,
                                                 const float* __restrict__ bc,
                                                 float* __restrict__ E) {
    __shared__ float sAt[64 * 132];
    __shared__ float sW [64 * 128];
    const int tid = threadIdx.x;
    const int rowBase = blockIdx.x * 128;
    const int r0 = (tid >> 4) * 8;
    const int c1 = (tid & 15) * 4;

    float acc[8][8];
    #pragma unroll
    for (int u = 0; u < 8; ++u)
        #pragma unroll
        for (int q = 0; q < 8; ++q) acc[u][q] = 0.f;

    for (int kh = 0; kh < 2; ++kh) {
        if (kh) __syncthreads();
        for (int i = tid; i < 2048; i += 256)
            ((float4*)sW)[i] = ((const float4*)Wc)[kh * 2048 + i];
        for (int i = tid; i < 2048; i += 256) {
            int r  = i >> 4;
            int kq = (i & 15) * 4;
            float4 v = make_float4(0.f, 0.f, 0.f, 0.f);
            if (rowBase + r < VOCAB)
                v = *(const float4*)&emb[(long long)(rowBase + r) * DIM + kh * 64 + kq];
            sAt[(kq + 0) * 132 + r] = v.x;
            sAt[(kq + 1) * 132 + r] = v.y;
            sAt[(kq + 2) * 132 + r] = v.z;
            sAt[(kq + 3) * 132 + r] = v.w;
        }
        __syncthreads();

        #pragma unroll 4
        for (int k = 0; k < 64; ++k) {
            float4 a0 = *(float4*)&sAt[k * 132 + r0];
            float4 a1 = *(float4*)&sAt[k * 132 + r0 + 4];
            float4 w0 = *(float4*)&sW [k * 128 + c1];
            float4 w1 = *(float4*)&sW [k * 128 + 64 + c1];
            float av[8] = {a0.x, a0.y, a0.z, a0.w, a1.x, a1.y, a1.z, a1.w};
            #pragma unroll
            for (int u = 0; u < 8; ++u) {
                acc[u][0] += av[u] * w0.x; acc[u][1] += av[u] * w0.y;
                acc[u][2] += av[u] * w0.z; acc[u][3] += av[u] * w0.w;
                acc[u][4] += av[u] * w1.x; acc[u][5] += av[u] * w1.y;
                acc[u][6] += av[u] * w1.z; acc[u][7] += av[u] * w1.w;
            }
        }
    }

    float4 b0 = *(const float4*)&bc[c1];
    float4 b1 = *(const float4*)&bc[64 + c1];
    #pragma unroll
    for (int u = 0; u < 8; ++u) {
        int r = rowBase + r0 + u;
        if (r < VOCAB) {
            float4 o0 = make_float4(acc[u][0]+b0.x, acc[u][1]+b0.y, acc[u][2]+b0.z, acc[u][3]+b0.w);
            float4 o1 = make_float4(acc[u][4]+b1.x, acc[u][5]+b1.y, acc[u][6]+b1.z, acc[u][7]+b1.w);
            *(float4*)&E[(long long)r * DIM + c1]      = o0;
            *(float4*)&E[(long long)r * DIM + 64 + c1] = o1;
        }
    }
}

// ---------------- fused gather + prefix-scan + subtree-max ----------------
// Gather is global_load_lds DMA (zero data VGPRs -> no scratch spill; r7 had
// 128 MB of spill WRITE from the val[8] staging array at the 512-thread VGPR
// heuristic). __launch_bounds__(512,4) caps at 128 VGPR so the scan's x[32]
// truly lives in registers across the partials barrier. Chunk offset is folded
// into the scan write-back, so extract reads only S[e]/S[t-1].
// Grid: slice = blockIdx>>9, tree = blockIdx&511 -> all 4 slices of a tree are
// congruent mod 8 -> same XCD under round-robin -> E fetched once per XCD.
__global__ __launch_bounds__(512, 4) void scan_k(const int* __restrict__ tokD,
                                                 const unsigned short* __restrict__ endD,
                                                 const float* __restrict__ E,
                                                 float* __restrict__ out) {
    const int b = blockIdx.x & 511, s = blockIdx.x >> 9, tid = threadIdx.x;
    const long long base = (long long)b * NPB;
    __shared__ float S[NPB * 32];             // 64000 B
    __shared__ int tokL[NPB];                 // 2000 B
    __shared__ unsigned short endL[NPB];      // 1000 B
    __shared__ float partials[16 * 32];       // 2048 B
    __shared__ float wmax[8 * 32];            // 1024 B

    if (tid < NPB) {
        tokL[tid] = tokD[base + tid];
        endL[tid] = endD[base + tid];
    }
    __syncthreads();

    // gather: 4000 float4 tasks; direct global->LDS DMA, lane-contiguous dest
    #pragma unroll
    for (int u = 0; u < 8; ++u) {
        int i = tid + u * 512;
        if (i < NPB * 8) {
            const float* g = &E[(long long)tokL[i >> 3] * DIM + s * 32 + (i & 7) * 4];
            __builtin_amdgcn_global_load_lds(
                (const __attribute__((address_space(1))) void*)g,
                (__attribute__((address_space(3))) void*)&S[i * 4], 16, 0, 0);
        }
    }
    __syncthreads();

    // blocked inclusive scan; x[32] in VGPRs; offset folded into write-back
    const int j = tid & 31, c = tid >> 5;
    float x[32];
    {
        float run = 0.f;
        #pragma unroll
        for (int k = 0; k < 32; ++k) {
            int t = c * 32 + k;
            float v = (t < NPB) ? S[t * 32 + j] : 0.f;
            run += v; x[k] = run;
        }
        partials[c * 32 + j] = run;
    }
    __syncthreads();
    {
        float off = 0.f;
        for (int cc = 0; cc < c; ++cc) off += partials[cc * 32 + j];
        #pragma unroll
        for (int k = 0; k < 32; ++k) {
            int t = c * 32 + k;
            if (t < NPB) S[t * 32 + j] = x[k] + off;
        }
    }
    __syncthreads();

    // subtree_sum(t) = S[end[t]] - S[t-1]; fused max
    float m = -INFINITY;
    #pragma unroll 4
    for (int u = 0; u < 32; ++u) {
        int i = tid + u * 512;                // i&31 == j
        if (i < NPB * 32) {
            int t = i >> 5;
            float hi = S[(int)endL[t] * 32 + j];
            float lo = (t > 0) ? S[(t - 1) * 32 + j] : 0.f;
            m = fmaxf(m, hi - lo);
        }
    }
    m = fmaxf(m, __shfl_down(m, 32));
    if ((tid & 63) < 32) wmax[(tid >> 6) * 32 + j] = m;
    __syncthreads();
    if (tid < 32) {
        float mm = wmax[tid];
        #pragma unroll
        for (int w = 1; w < 8; ++w) mm = fmaxf(mm, wmax[w * 32 + tid]);
        out[b * DIM + s * 32 + tid] = fmaxf(mm, 0.0f);
    }
}

extern "C" void kernel_launch(void* const* d_in, const int* in_sizes, int n_in,
                              void* d_out, int out_size, void* d_ws, size_t ws_size,
                              hipStream_t stream) {
    const int*   tokens = (const int*)d_in[0];
    const int*   parent = (const int*)d_in[1];
    const int*   depth  = (const int*)d_in[2];
    // d_in[3] = node2batch (unused: node2batch[n] == n / 500 by construction)
    const float* emb    = (const float*)d_in[4];
    const float* Wc     = (const float*)d_in[5];
    const float* bc     = (const float*)d_in[6];
    float*       out    = (float*)d_out;

    float*          E    = (float*)d_ws;                            // 25.6 MB
    int*            tokD = (int*)(E + (long long)VOCAB * DIM);      // 1 MB
    unsigned short* endD = (unsigned short*)(tokD + B_BATCH * NPB); // 0.5 MB

    prep_k<<<B_BATCH, 256, 0, stream>>>(tokens, parent, depth, tokD, endD);
    gemm_E<<<(VOCAB + 127) / 128, 256, 0, stream>>>(emb, Wc, bc, E);
    scan_k<<<B_BATCH * 4, 512, 0, stream>>>(tokD, endD, E, out);
}

// Round 9
// 150.822 us; speedup vs baseline: 2.1893x; 1.1330x over previous
//
#include <hip/hip_runtime.h>
#include <hip/hip_bf16.h>

#define B_BATCH 512
#define NPB     500
#define DIM     128
#define VOCAB   50000
#define MAXD    40
#define NPREP   512
#define NGEMM   ((VOCAB + 63) / 64)   // 782

typedef short bf16x8 __attribute__((ext_vector_type(8)));
typedef float f32x4  __attribute__((ext_vector_type(4)));

__device__ __forceinline__ unsigned short f2bf(float x) {
    unsigned u = __float_as_uint(x);
    return (unsigned short)((u + 0x7fffu + ((u >> 16) & 1u)) >> 16);   // RTNE
}

// ---------------- fused prep (blocks 0..511) + MFMA gemm (blocks 512..1293) ----
// prep: per-tree DFS order (tin/end) via fully parallel level-synchronous
// passes (round-7 algorithm, unchanged). gemm: E = bf16(emb) @ bf16(Wc) + bc
// with v_mfma_f32_16x16x32_bf16, fp32 accumulate. Fusing the two dispatches
// overlaps prep (~15us, small grid) under gemm instead of serializing.
__global__ __launch_bounds__(256, 3) void prep_gemm(const int* __restrict__ tokens,
                                                    const int* __restrict__ parent,
                                                    const int* __restrict__ depth,
                                                    const float* __restrict__ emb,
                                                    const float* __restrict__ Wc,
                                                    const float* __restrict__ bc,
                                                    int* __restrict__ tokD,
                                                    unsigned short* __restrict__ endD,
                                                    float* __restrict__ E) {
    __shared__ __align__(16) char smem[50176];
    const int tid = threadIdx.x;

    if (blockIdx.x >= NPREP) {
        // ================= GEMM branch =================
        // sA: [m][k] bf16, 64 rows, stride 136 (pad 8 -> bank rotation, <=2-way)
        // sB: B-frag order: ((kc*8+nt)*64 + lane)*8 + j  -> frag load = ds_read_b128
        unsigned short* sA = (unsigned short*)smem;            // 17408 B
        unsigned short* sB = (unsigned short*)(smem + 17408);  // 32768 B
        const int rowBase = (blockIdx.x - NPREP) * 64;

        // stage Wc -> bf16, swizzled to B-fragment order
        for (int i = tid; i < DIM * DIM; i += 256) {
            int k = i >> 7, n = i & 127;
            int kc = k >> 5, q = (k >> 3) & 3, jj = k & 7;
            int nt = n >> 4, ln = q * 16 + (n & 15);
            sB[((kc * 8 + nt) * 64 + ln) * 8 + jj] = f2bf(Wc[i]);
        }
        // stage 64 emb rows -> bf16 [m][k] stride 136
        for (int i = tid; i < 64 * 32; i += 256) {
            int r = i >> 5, k4 = (i & 31) * 4;
            float4 v = make_float4(0.f, 0.f, 0.f, 0.f);
            if (rowBase + r < VOCAB)
                v = *(const float4*)&emb[(long long)(rowBase + r) * DIM + k4];
            unsigned long long pk =  (unsigned long long)f2bf(v.x)
                                  | ((unsigned long long)f2bf(v.y) << 16)
                                  | ((unsigned long long)f2bf(v.z) << 32)
                                  | ((unsigned long long)f2bf(v.w) << 48);
            *(unsigned long long*)&sA[r * 136 + k4] = pk;
        }
        __syncthreads();

        const int lane = tid & 63, w = tid >> 6;   // wave w: rows w*16..w*16+15
        const int q = lane >> 4, mc = lane & 15;

        f32x4 acc[8];
        #pragma unroll
        for (int nt = 0; nt < 8; ++nt) acc[nt] = (f32x4){0.f, 0.f, 0.f, 0.f};

        #pragma unroll
        for (int kc = 0; kc < 4; ++kc) {
            bf16x8 a = *(const bf16x8*)&sA[(w * 16 + mc) * 136 + kc * 32 + q * 8];
            #pragma unroll
            for (int nt = 0; nt < 8; ++nt) {
                bf16x8 bf = *(const bf16x8*)&sB[((kc * 8 + nt) * 64 + lane) * 8];
                acc[nt] = __builtin_amdgcn_mfma_f32_16x16x32_bf16(a, bf, acc[nt], 0, 0, 0);
            }
        }

        // epilogue: C/D layout row=(lane>>4)*4+reg, col=lane&15 per 16x16 tile
        #pragma unroll
        for (int nt = 0; nt < 8; ++nt) {
            float bcv = bc[nt * 16 + mc];
            #pragma unroll
            for (int r = 0; r < 4; ++r) {
                int grow = rowBase + w * 16 + q * 4 + r;
                if (grow < VOCAB)
                    E[(long long)grow * DIM + nt * 16 + mc] = acc[nt][r] + bcv;
            }
        }
        return;
    }

    // ================= PREP branch =================
    int*            sizeL  = (int*)smem;                       // 2000
    int*            pack   = (int*)(smem + 2000);              // 2000
    int*            tokL   = (int*)(smem + 4000);              // 2000
    int*            tmpTok = (int*)(smem + 6000);              // 2000
    int*            hist   = (int*)(smem + 8000);              // 164
    int*            off    = (int*)(smem + 8164);              // 164
    int*            cur    = (int*)(smem + 8328);              // 164
    int*            sdmax  = (int*)(smem + 8492);              // 4
    unsigned short* parL   = (unsigned short*)(smem + 8496);   // 1000
    unsigned short* depL   = (unsigned short*)(smem + 9496);   // 1000
    unsigned short* sibp   = (unsigned short*)(smem + 10496);  // 1000
    unsigned short* tinL   = (unsigned short*)(smem + 11496);  // 1000
    unsigned short* bucket = (unsigned short*)(smem + 12496);  // 1000
    unsigned short* tmpEnd = (unsigned short*)(smem + 13496);  // 1000

    const int b = blockIdx.x;
    const long long base = (long long)b * NPB;

    if (tid <= MAXD) hist[tid] = 0;
    __syncthreads();
    for (int n = tid; n < NPB; n += 256) {
        int d = depth[base + n];
        depL[n]  = (unsigned short)d;
        parL[n]  = (unsigned short)(n == 0 ? 0 : (int)(parent[base + n] - base));
        tokL[n]  = tokens[base + n];
        sizeL[n] = 1;
        if (n > 0) atomicAdd(&hist[d], 1);
    }
    __syncthreads();

    if (tid < 64) {
        int h = (tid >= 1 && tid <= MAXD) ? hist[tid] : 0;
        int x = h;
        #pragma unroll
        for (int o = 1; o < 64; o <<= 1) { int y = __shfl_up(x, o, 64); if (tid >= o) x += y; }
        if (tid >= 1 && tid <= MAXD) { off[tid] = x - h; cur[tid] = x - h; }
        int dm = (h > 0) ? tid : 0;
        #pragma unroll
        for (int o = 32; o; o >>= 1) dm = max(dm, __shfl_down(dm, o));
        if (tid == 0) *sdmax = dm;
    }
    __syncthreads();

    for (int n = 1 + tid; n < NPB; n += 256)
        bucket[atomicAdd(&cur[depL[n]], 1)] = (unsigned short)n;
    __syncthreads();
    const int dmax = *sdmax;

    // bottom-up subtree sizes (children final before parent)
    for (int d = dmax; d >= 1; --d) {
        int c = hist[d], o = off[d];
        for (int i = tid; i < c; i += 256) {
            int n = bucket[o + i];
            atomicAdd(&sizeL[parL[n]], sizeL[n]);
        }
        __syncthreads();
    }

    for (int n = tid; n < NPB; n += 256) pack[n] = (int)parL[n] | (sizeL[n] << 16);
    __syncthreads();

    {   // sibp[n] = sizes of smaller-index same-parent siblings (broadcast loop)
        int n0 = tid, n1 = tid + 256;
        int p0 = parL[n0];
        int p1 = (n1 < NPB) ? parL[n1] : -1;
        int a0 = 0, a1 = 0;
        for (int m = 1; m < NPB; ++m) {
            int pk = pack[m];
            int pm = pk & 0xffff, sm = pk >> 16;
            if (m < n0 && pm == p0) a0 += sm;
            if (m < n1 && pm == p1) a1 += sm;
        }
        if (n0 >= 1) sibp[n0] = (unsigned short)a0;
        if (n1 >= 1 && n1 < NPB) sibp[n1] = (unsigned short)a1;
        if (tid == 0) tinL[0] = 0;
    }
    __syncthreads();

    // top-down preorder positions
    for (int d = 1; d <= dmax; ++d) {
        int c = hist[d], o = off[d];
        for (int i = tid; i < c; i += 256) {
            int n = bucket[o + i];
            tinL[n] = (unsigned short)((int)tinL[parL[n]] + 1 + (int)sibp[n]);
        }
        __syncthreads();
    }

    for (int n = tid; n < NPB; n += 256) {
        int t = tinL[n];
        tmpTok[t] = tokL[n];
        tmpEnd[t] = (unsigned short)(t + sizeL[n] - 1);
    }
    __syncthreads();
    for (int t = tid; t < NPB; t += 256) {
        tokD[base + t] = tmpTok[t];
        endD[base + t] = tmpEnd[t];
    }
}

// ---------------- fused gather + prefix-scan + subtree-max ----------------
// Gather: global->LDS DMA. Scan: x[32] in VGPRs, offset folded into regs.
// Extract: lo comes FROM REGISTERS (x[k-1], or off at chunk head — S[c*32-1]
// is exactly the chunk offset), endL reads are same-address broadcasts across
// the 32 threads sharing a chunk; only `hi = S[end[t]]` touches LDS (~33 LDS
// ops/thread vs ~96 in r8's extract).
__global__ __launch_bounds__(512, 4) void scan_k(const int* __restrict__ tokD,
                                                 const unsigned short* __restrict__ endD,
                                                 const float* __restrict__ E,
                                                 float* __restrict__ out) {
    const int b = blockIdx.x & 511, s = blockIdx.x >> 9, tid = threadIdx.x;
    const long long base = (long long)b * NPB;
    __shared__ float S[NPB * 32];             // 64000 B
    __shared__ int tokL[NPB];
    __shared__ unsigned short endL[NPB];
    __shared__ float partials[16 * 32];
    __shared__ float wmax[8 * 32];

    if (tid < NPB) {
        tokL[tid] = tokD[base + tid];
        endL[tid] = endD[base + tid];
    }
    __syncthreads();

    #pragma unroll
    for (int u = 0; u < 8; ++u) {
        int i = tid + u * 512;
        if (i < NPB * 8) {
            const float* g = &E[(long long)tokL[i >> 3] * DIM + s * 32 + (i & 7) * 4];
            __builtin_amdgcn_global_load_lds(
                (const __attribute__((address_space(1))) void*)g,
                (__attribute__((address_space(3))) void*)&S[i * 4], 16, 0, 0);
        }
    }
    __syncthreads();

    const int j = tid & 31, c = tid >> 5;
    float x[32];
    {
        float run = 0.f;
        #pragma unroll
        for (int k = 0; k < 32; ++k) {
            int t = c * 32 + k;
            float v = (t < NPB) ? S[t * 32 + j] : 0.f;
            run += v; x[k] = run;
        }
        partials[c * 32 + j] = run;
    }
    __syncthreads();
    float off = 0.f;
    for (int cc = 0; cc < c; ++cc) off += partials[cc * 32 + j];
    #pragma unroll
    for (int k = 0; k < 32; ++k) {
        int t = c * 32 + k;
        x[k] += off;
        if (t < NPB) S[t * 32 + j] = x[k];
    }
    __syncthreads();

    // extract over OWN chunk: lo from registers, hi = S[end[t]] (bank j, free)
    float m = -INFINITY;
    #pragma unroll
    for (int k = 0; k < 32; ++k) {
        int t = c * 32 + k;
        if (t < NPB) {
            float hi = S[(int)endL[t] * 32 + j];
            float lo = (k > 0) ? x[k - 1] : off;
            m = fmaxf(m, hi - lo);
        }
    }
    m = fmaxf(m, __shfl_down(m, 32));
    if ((tid & 63) < 32) wmax[(tid >> 6) * 32 + j] = m;
    __syncthreads();
    if (tid < 32) {
        float mm = wmax[tid];
        #pragma unroll
        for (int w = 1; w < 8; ++w) mm = fmaxf(mm, wmax[w * 32 + tid]);
        out[b * DIM + s * 32 + tid] = fmaxf(mm, 0.0f);
    }
}

extern "C" void kernel_launch(void* const* d_in, const int* in_sizes, int n_in,
                              void* d_out, int out_size, void* d_ws, size_t ws_size,
                              hipStream_t stream) {
    const int*   tokens = (const int*)d_in[0];
    const int*   parent = (const int*)d_in[1];
    const int*   depth  = (const int*)d_in[2];
    // d_in[3] = node2batch (unused: node2batch[n] == n / 500 by construction)
    const float* emb    = (const float*)d_in[4];
    const float* Wc     = (const float*)d_in[5];
    const float* bc     = (const float*)d_in[6];
    float*       out    = (float*)d_out;

    float*          E    = (float*)d_ws;                            // 25.6 MB
    int*            tokD = (int*)(E + (long long)VOCAB * DIM);      // 1 MB
    unsigned short* endD = (unsigned short*)(tokD + B_BATCH * NPB); // 0.5 MB

    prep_gemm<<<NPREP + NGEMM, 256, 0, stream>>>(tokens, parent, depth,
                                                 emb, Wc, bc, tokD, endD, E);
    scan_k<<<B_BATCH * 4, 512, 0, stream>>>(tokD, endD, E, out);
}